// Round 5
// baseline (149.020 us; speedup 1.0000x reference)
//
#include <hip/hip_runtime.h>
#include <hip/hip_bf16.h>
#include <hip/hip_fp16.h>

// RoIAlign (FPN, 4 levels) + SR=2x2 sample-mean + 2x2 stride-1 avg pool.
// B=2, N=512 rois, C=256, PH=PW=7, output (B*N, C*6*6) fp32.
//
// Round 5: gather LDS cut to ~22 KB (two-phase 128-channel output staging,
// results held in registers) -> 7 blocks/CU instead of 3-4. Everything else
// as R4: fp16 channels-last transposed features, half2 channel-pair taps,
// folded bilinear weights in LDS.

#define PH 7
#define C_CH 256
#define N_ROI 512
#define H0 160

// level sizes (P = H*W)
#define P0 25600
#define P1 6400
#define P2 1600
#define P3 400
// half-element offsets into ws for each transposed level (B=2, C=256)
#define OFF0 0ull
#define OFF1 (OFF0 + 2ull * C_CH * P0)
#define OFF2 (OFF1 + 2ull * C_CH * P1)
#define OFF3 (OFF2 + 2ull * C_CH * P2)
#define WS_HALFS (OFF3 + 2ull * C_CH * P3)   // 17,408,000 halves = 34.8 MB

// tile counts per level: ceil(P/64) * 4 (c-tiles) * 2 (batch)
#define NB0 (400 * 8)
#define NB1 (100 * 8)
#define NB2 (25 * 8)
#define NB3 (7 * 8)
#define NB_ALL (NB0 + NB1 + NB2 + NB3)

// ------------- fused (B,C,P) -> (B,P,C) transpose, fp32 -> fp16 -------------
__global__ __launch_bounds__(256) void transpose_f16_kernel(
    const float* __restrict__ f0, const float* __restrict__ f1,
    const float* __restrict__ f2, const float* __restrict__ f3,
    __half* __restrict__ ws)
{
    __shared__ float tile[64 * 65];
    int bid = blockIdx.x;
    const float* in; __half* outp; int P;
    if (bid < NB0)                  {              in = f0; outp = ws + OFF0; P = P0; }
    else if (bid < NB0 + NB1)       { bid -= NB0;  in = f1; outp = ws + OFF1; P = P1; }
    else if (bid < NB0 + NB1 + NB2) { bid -= NB0 + NB1; in = f2; outp = ws + OFF2; P = P2; }
    else                            { bid -= NB0 + NB1 + NB2; in = f3; outp = ws + OFF3; P = P3; }
    const int tiles_p = (P + 63) >> 6;
    const int tp   = bid % tiles_p;
    const int rest = bid / tiles_p;
    const int c0 = (rest & 3) << 6;
    const int b  = rest >> 2;
    const int p0 = tp << 6;
    const int pmax = P - p0;            // >=64 except last P3 tile (16)

    const int t = threadIdx.x;
    // phase 1: float4 loads along p, scalar LDS writes (row stride 65)
    const int pc  = (t & 15) << 2;      // 0,4,...,60
    const int cc0 = t >> 4;             // 0..15
    const float* A = in + ((size_t)b * C_CH + c0 + cc0) * (size_t)P + p0 + pc;
    if (pc < pmax) {
        #pragma unroll
        for (int k = 0; k < 4; ++k) {
            const float4 v = *(const float4*)(A + (size_t)(16 * k) * P);
            float* dst = tile + (cc0 + 16 * k) * 65 + pc;
            dst[0] = v.x; dst[1] = v.y; dst[2] = v.z; dst[3] = v.w;
        }
    }
    __syncthreads();
    // phase 2: pack channel pairs, half2 stores coalesced along c
    const int c2  = t & 31;
    const int pr0 = t >> 5;             // 0..7
    __half2* O = (__half2*)outp + ((size_t)b * P + p0) * (C_CH / 2) + (c0 >> 1) + c2;
    #pragma unroll
    for (int k = 0; k < 8; ++k) {
        const int pp = pr0 + 8 * k;
        if (pp < pmax) {
            const float fx = tile[(2 * c2)     * 65 + pp];
            const float fy = tile[(2 * c2 + 1) * 65 + pp];
            O[(size_t)pp * (C_CH / 2)] = __floats2half2_rn(fx, fy);
        }
    }
}

// ---------------- main gather kernel (fp16 channels-last) ----------------
__global__ __launch_bounds__(256) void roialign_kernel(
    const __half* __restrict__ ws,
    const float* __restrict__ rois, float* __restrict__ out)
{
    const int roi = blockIdx.x;            // 0 .. B*N-1
    const int b   = roi / N_ROI;
    const float* r = rois + (size_t)roi * 7;

    __shared__ int    s_y0[14], s_y1[14], s_x0[14], s_x1[14];  // half2-unit offsets
    __shared__ float  s_ly[14], s_lx[14], s_vy[14], s_vx[14];
    __shared__ float4 s_w[14][14];         // folded weights (x0.25, validity)
    __shared__ float  s_out[128 * 36];     // one 128-channel phase: 18432 B

    const int lev = (int)r[6];
    int H; const __half* ft;
    if      (lev == 0) { H = 160; ft = ws + OFF0; }
    else if (lev == 1) { H = 80;  ft = ws + OFF1; }
    else if (lev == 2) { H = 40;  ft = ws + OFF2; }
    else               { H = 20;  ft = ws + OFF3; }
    const int W = H;
    const int P = H * W;

    const float scale = (8.0f * (float)H) / (float)H0;
    const float x1 = r[1] * scale, y1 = r[2] * scale;
    const float x2 = r[3] * scale, y2 = r[4] * scale;
    const float bw = fmaxf(x2 - x1, 1.0f) * (1.0f / (float)PH);
    const float bh = fmaxf(y2 - y1, 1.0f) * (1.0f / (float)PH);

    const int t = threadIdx.x;
    if (t < 14) {
        const float off = (float)(t >> 1) + 0.25f + 0.5f * (float)(t & 1);
        const float ys  = y1 + off * bh;
        s_vy[t] = (ys >= -1.0f && ys <= (float)H) ? 1.0f : 0.0f;
        const float y  = fminf(fmaxf(ys, 0.0f), (float)(H - 1));
        const float yf = floorf(y);
        s_ly[t] = y - yf;
        const int y0 = (int)yf;
        s_y0[t] = y0 * (W * (C_CH / 2));
        s_y1[t] = min(y0 + 1, H - 1) * (W * (C_CH / 2));
    } else if (t < 28) {
        const int k = t - 14;
        const float off = (float)(k >> 1) + 0.25f + 0.5f * (float)(k & 1);
        const float xs  = x1 + off * bw;
        s_vx[k] = (xs >= -1.0f && xs <= (float)W) ? 1.0f : 0.0f;
        const float x  = fminf(fmaxf(xs, 0.0f), (float)(W - 1));
        const float xf = floorf(x);
        s_lx[k] = x - xf;
        const int x0 = (int)xf;
        s_x0[k] = x0 * (C_CH / 2);
        s_x1[k] = min(x0 + 1, W - 1) * (C_CH / 2);
    }
    __syncthreads();

    if (t < 196) {
        const int sy = t / 14, sx = t - 14 * sy;
        const float ly = s_ly[sy], lx = s_lx[sx];
        const float v  = 0.25f * s_vy[sy] * s_vx[sx];
        const float hy = v * ly;
        const float my = v - hy;
        s_w[sy][sx] = make_float4(my - my * lx, my * lx, hy - hy * lx, hy * lx);
    }
    __syncthreads();

    const int g  = t >> 7;                 // row group: 0 -> bins 0..3, 1 -> 3..6
    const int c2 = t & 127;                // channel pair (channels 2c2, 2c2+1)
    const __half2* __restrict__ cbase =
        (const __half2*)ft + (size_t)b * P * (C_CH / 2) + c2;

    const int i0 = g ? 3 : 0;
    float prevx[7], prevy[7];
    float outx[18], outy[18];              // 3 pooled rows x 6, per channel

    for (int i = i0; i < i0 + 4; ++i) {
        float curx[7], cury[7];
        #pragma unroll
        for (int j = 0; j < 7; ++j) { curx[j] = 0.0f; cury[j] = 0.0f; }

        #pragma unroll
        for (int syk = 0; syk < 2; ++syk) {
            const int sy = 2 * i + syk;
            const __half2* __restrict__ q0 = cbase + s_y0[sy];
            const __half2* __restrict__ q1 = cbase + s_y1[sy];
            #pragma unroll
            for (int j = 0; j < 7; ++j) {
                #pragma unroll
                for (int sxk = 0; sxk < 2; ++sxk) {
                    const int sx = 2 * j + sxk;
                    const float4 w = s_w[sy][sx];
                    const int xa = s_x0[sx], xb = s_x1[sx];
                    const __half2 h00 = q0[xa], h01 = q0[xb];
                    const __half2 h10 = q1[xa], h11 = q1[xb];
                    curx[j] += w.x * __low2float(h00)  + w.y * __low2float(h01)
                             + w.z * __low2float(h10)  + w.w * __low2float(h11);
                    cury[j] += w.x * __high2float(h00) + w.y * __high2float(h01)
                             + w.z * __high2float(h10) + w.w * __high2float(h11);
                }
            }
        }

        if (i > i0) {
            const int p = i - i0 - 1;      // local pooled row 0..2
            #pragma unroll
            for (int j = 0; j < 6; ++j) {
                outx[p * 6 + j] = 0.25f * (prevx[j] + prevx[j + 1] + curx[j] + curx[j + 1]);
                outy[p * 6 + j] = 0.25f * (prevy[j] + prevy[j + 1] + cury[j] + cury[j + 1]);
            }
        }
        #pragma unroll
        for (int j = 0; j < 7; ++j) { prevx[j] = curx[j]; prevy[j] = cury[j]; }
    }

    // two-phase staged output: 128 channels at a time (18 KB LDS)
    float* __restrict__ orow = out + (size_t)roi * (C_CH * 36);
    const int lc   = c2 & 63;              // channel pair within phase
    const int mine = c2 >> 6;              // which phase this thread writes in
    const int rofs = g ? 18 : 0;           // rows 0-2 vs 3-5

    #pragma unroll
    for (int ph = 0; ph < 2; ++ph) {
        if (ph) __syncthreads();           // previous copy done before overwrite
        if (mine == ph) {
            float* __restrict__ o0 = s_out + (2 * lc)     * 36 + rofs;
            float* __restrict__ o1 = s_out + (2 * lc + 1) * 36 + rofs;
            #pragma unroll
            for (int e = 0; e < 18; ++e) { o0[e] = outx[e]; o1[e] = outy[e]; }
        }
        __syncthreads();
        float* __restrict__ dst = orow + ph * (128 * 36);
        #pragma unroll
        for (int e = t; e < 128 * 36; e += 256)
            dst[e] = s_out[e];
    }
}

// ---------------- fallback: direct fp32 gather (no workspace) ----------------
__global__ __launch_bounds__(256) void roialign_direct_kernel(
    const float* __restrict__ f0, const float* __restrict__ f1,
    const float* __restrict__ f2, const float* __restrict__ f3,
    const float* __restrict__ rois, float* __restrict__ out)
{
    const int roi = blockIdx.x;
    const int b   = roi / N_ROI;
    const float* r = rois + (size_t)roi * 7;

    __shared__ int   s_y0[14], s_y1[14], s_x0[14], s_x1[14];
    __shared__ float s_ly[14], s_lx[14], s_vy[14], s_vx[14];

    const int lev = (int)r[6];
    int H; const float* f;
    if      (lev == 0) { H = 160; f = f0; }
    else if (lev == 1) { H = 80;  f = f1; }
    else if (lev == 2) { H = 40;  f = f2; }
    else               { H = 20;  f = f3; }
    const int W = H;
    const float scale = (8.0f * (float)H) / (float)H0;
    const float x1 = r[1] * scale, y1 = r[2] * scale;
    const float x2 = r[3] * scale, y2 = r[4] * scale;
    const float bw = fmaxf(x2 - x1, 1.0f) * (1.0f / (float)PH);
    const float bh = fmaxf(y2 - y1, 1.0f) * (1.0f / (float)PH);

    const int t = threadIdx.x;
    if (t < 14) {
        const float off = (float)(t >> 1) + 0.25f + 0.5f * (float)(t & 1);
        const float ys  = y1 + off * bh;
        s_vy[t] = (ys >= -1.0f && ys <= (float)H) ? 1.0f : 0.0f;
        const float y  = fminf(fmaxf(ys, 0.0f), (float)(H - 1));
        const float yf = floorf(y);
        s_ly[t] = y - yf;
        const int y0 = (int)yf;
        s_y0[t] = y0 * W;
        s_y1[t] = min(y0 + 1, H - 1) * W;
    } else if (t < 28) {
        const int k = t - 14;
        const float off = (float)(k >> 1) + 0.25f + 0.5f * (float)(k & 1);
        const float xs  = x1 + off * bw;
        s_vx[k] = (xs >= -1.0f && xs <= (float)W) ? 1.0f : 0.0f;
        const float x  = fminf(fmaxf(xs, 0.0f), (float)(W - 1));
        const float xf = floorf(x);
        s_lx[k] = x - xf;
        const int x0 = (int)xf;
        s_x0[k] = x0;
        s_x1[k] = min(x0 + 1, W - 1);
    }
    __syncthreads();

    const int c = t;
    const float* __restrict__ fc = f + ((size_t)b * C_CH + c) * (size_t)(H * W);
    float* __restrict__ o_base = out + (size_t)roi * (C_CH * 36) + (size_t)c * 36;
    float prev[PH];

    for (int i = 0; i < PH; ++i) {
        const int   sy0 = 2 * i, sy1 = 2 * i + 1;
        const float lya = s_ly[sy0], vya = s_vy[sy0];
        const float lyb = s_ly[sy1], vyb = s_vy[sy1];
        const float* ra0 = fc + s_y0[sy0];
        const float* ra1 = fc + s_y1[sy0];
        const float* rb0 = fc + s_y0[sy1];
        const float* rb1 = fc + s_y1[sy1];
        float cur[PH];
        #pragma unroll
        for (int j = 0; j < PH; ++j) {
            float acc = 0.0f;
            #pragma unroll
            for (int sj = 0; sj < 2; ++sj) {
                const int   sx = 2 * j + sj;
                const int   x0 = s_x0[sx], x1i = s_x1[sx];
                const float lx = s_lx[sx], vx = s_vx[sx];
                {
                    const float f00 = ra0[x0], f01 = ra0[x1i];
                    const float f10 = ra1[x0], f11 = ra1[x1i];
                    const float top = f00 + lx * (f01 - f00);
                    const float bot = f10 + lx * (f11 - f10);
                    acc += (vya * vx) * (top + lya * (bot - top));
                }
                {
                    const float f00 = rb0[x0], f01 = rb0[x1i];
                    const float f10 = rb1[x0], f11 = rb1[x1i];
                    const float top = f00 + lx * (f01 - f00);
                    const float bot = f10 + lx * (f11 - f10);
                    acc += (vyb * vx) * (top + lyb * (bot - top));
                }
            }
            cur[j] = acc * 0.25f;
        }
        if (i > 0) {
            float* o = o_base + (size_t)(i - 1) * 6;
            #pragma unroll
            for (int j = 0; j < 6; ++j)
                o[j] = 0.25f * (prev[j] + prev[j + 1] + cur[j] + cur[j + 1]);
        }
        #pragma unroll
        for (int j = 0; j < PH; ++j) prev[j] = cur[j];
    }
}

extern "C" void kernel_launch(void* const* d_in, const int* in_sizes, int n_in,
                              void* d_out, int out_size, void* d_ws, size_t ws_size,
                              hipStream_t stream) {
    const float* f0   = (const float*)d_in[0];
    const float* f1   = (const float*)d_in[1];
    const float* f2   = (const float*)d_in[2];
    const float* f3   = (const float*)d_in[3];
    const float* rois = (const float*)d_in[4];
    float* out = (float*)d_out;

    const int n_rois = in_sizes[4] / 7;   // B*N = 1024
    const size_t need = WS_HALFS * sizeof(__half);

    if (d_ws != nullptr && ws_size >= need) {
        __half* ws = (__half*)d_ws;
        transpose_f16_kernel<<<NB_ALL, 256, 0, stream>>>(f0, f1, f2, f3, ws);
        roialign_kernel<<<n_rois, 256, 0, stream>>>(ws, rois, out);
    } else {
        roialign_direct_kernel<<<n_rois, 256, 0, stream>>>(f0, f1, f2, f3, rois, out);
    }
}

// Round 7
// 148.270 us; speedup vs baseline: 1.0051x; 1.0051x over previous
//
#include <hip/hip_runtime.h>
#include <hip/hip_bf16.h>
#include <hip/hip_fp16.h>

// RoIAlign (FPN, 4 levels) + SR=2x2 sample-mean + 2x2 stride-1 avg pool.
// B=2, N=512 rois, C=256, PH=PW=7, output (B*N, C*6*6) fp32.
//
// Round 7: fix R6's staging overflow — each channel PAIR needs 36 float2
// (72 floats), not 33. Pair-major float2[128][36] staging (40.4 KB total
// LDS -> 4 blocks/CU), in-loop row emission (low VGPR), single-barrier
// coalesced epilogue. Otherwise identical to the R4 gather loop.

#define PH 7
#define C_CH 256
#define N_ROI 512
#define H0 160

// level sizes (P = H*W)
#define P0 25600
#define P1 6400
#define P2 1600
#define P3 400
// half-element offsets into ws for each transposed level (B=2, C=256)
#define OFF0 0ull
#define OFF1 (OFF0 + 2ull * C_CH * P0)
#define OFF2 (OFF1 + 2ull * C_CH * P1)
#define OFF3 (OFF2 + 2ull * C_CH * P2)
#define WS_HALFS (OFF3 + 2ull * C_CH * P3)   // 17,408,000 halves = 34.8 MB

// tile counts per level: ceil(P/64) * 4 (c-tiles) * 2 (batch)
#define NB0 (400 * 8)
#define NB1 (100 * 8)
#define NB2 (25 * 8)
#define NB3 (7 * 8)
#define NB_ALL (NB0 + NB1 + NB2 + NB3)

// ------------- fused (B,C,P) -> (B,P,C) transpose, fp32 -> fp16 -------------
__global__ __launch_bounds__(256) void transpose_f16_kernel(
    const float* __restrict__ f0, const float* __restrict__ f1,
    const float* __restrict__ f2, const float* __restrict__ f3,
    __half* __restrict__ ws)
{
    __shared__ float tile[64 * 65];
    int bid = blockIdx.x;
    const float* in; __half* outp; int P;
    if (bid < NB0)                  {              in = f0; outp = ws + OFF0; P = P0; }
    else if (bid < NB0 + NB1)       { bid -= NB0;  in = f1; outp = ws + OFF1; P = P1; }
    else if (bid < NB0 + NB1 + NB2) { bid -= NB0 + NB1; in = f2; outp = ws + OFF2; P = P2; }
    else                            { bid -= NB0 + NB1 + NB2; in = f3; outp = ws + OFF3; P = P3; }
    const int tiles_p = (P + 63) >> 6;
    const int tp   = bid % tiles_p;
    const int rest = bid / tiles_p;
    const int c0 = (rest & 3) << 6;
    const int b  = rest >> 2;
    const int p0 = tp << 6;
    const int pmax = P - p0;            // >=64 except last P3 tile (16)

    const int t = threadIdx.x;
    // phase 1: float4 loads along p, scalar LDS writes (row stride 65)
    const int pc  = (t & 15) << 2;      // 0,4,...,60
    const int cc0 = t >> 4;             // 0..15
    const float* A = in + ((size_t)b * C_CH + c0 + cc0) * (size_t)P + p0 + pc;
    if (pc < pmax) {
        #pragma unroll
        for (int k = 0; k < 4; ++k) {
            const float4 v = *(const float4*)(A + (size_t)(16 * k) * P);
            float* dst = tile + (cc0 + 16 * k) * 65 + pc;
            dst[0] = v.x; dst[1] = v.y; dst[2] = v.z; dst[3] = v.w;
        }
    }
    __syncthreads();
    // phase 2: pack channel pairs, half2 stores coalesced along c
    const int c2  = t & 31;
    const int pr0 = t >> 5;             // 0..7
    __half2* O = (__half2*)outp + ((size_t)b * P + p0) * (C_CH / 2) + (c0 >> 1) + c2;
    #pragma unroll
    for (int k = 0; k < 8; ++k) {
        const int pp = pr0 + 8 * k;
        if (pp < pmax) {
            const float fx = tile[(2 * c2)     * 65 + pp];
            const float fy = tile[(2 * c2 + 1) * 65 + pp];
            O[(size_t)pp * (C_CH / 2)] = __floats2half2_rn(fx, fy);
        }
    }
}

// ---------------- main gather kernel (fp16 channels-last) ----------------
__global__ __launch_bounds__(256) void roialign_kernel(
    const __half* __restrict__ ws,
    const float* __restrict__ rois, float* __restrict__ out)
{
    const int roi = blockIdx.x;            // 0 .. B*N-1
    const int b   = roi / N_ROI;
    const float* r = rois + (size_t)roi * 7;

    __shared__ int    s_y0[14], s_y1[14], s_x0[14], s_x1[14];  // half2-unit offsets
    __shared__ float  s_ly[14], s_lx[14], s_vy[14], s_vx[14];
    __shared__ float4 s_w[14][14];         // folded weights (x0.25, validity)
    __shared__ float2 s_out2[128 * 36];    // pair-major: 36 float2 per pair = 36864 B

    const int lev = (int)r[6];
    int H; const __half* ft;
    if      (lev == 0) { H = 160; ft = ws + OFF0; }
    else if (lev == 1) { H = 80;  ft = ws + OFF1; }
    else if (lev == 2) { H = 40;  ft = ws + OFF2; }
    else               { H = 20;  ft = ws + OFF3; }
    const int W = H;
    const int P = H * W;

    const float scale = (8.0f * (float)H) / (float)H0;
    const float x1 = r[1] * scale, y1 = r[2] * scale;
    const float x2 = r[3] * scale, y2 = r[4] * scale;
    const float bw = fmaxf(x2 - x1, 1.0f) * (1.0f / (float)PH);
    const float bh = fmaxf(y2 - y1, 1.0f) * (1.0f / (float)PH);

    const int t = threadIdx.x;
    if (t < 14) {
        const float off = (float)(t >> 1) + 0.25f + 0.5f * (float)(t & 1);
        const float ys  = y1 + off * bh;
        s_vy[t] = (ys >= -1.0f && ys <= (float)H) ? 1.0f : 0.0f;
        const float y  = fminf(fmaxf(ys, 0.0f), (float)(H - 1));
        const float yf = floorf(y);
        s_ly[t] = y - yf;
        const int y0 = (int)yf;
        s_y0[t] = y0 * (W * (C_CH / 2));
        s_y1[t] = min(y0 + 1, H - 1) * (W * (C_CH / 2));
    } else if (t < 28) {
        const int k = t - 14;
        const float off = (float)(k >> 1) + 0.25f + 0.5f * (float)(k & 1);
        const float xs  = x1 + off * bw;
        s_vx[k] = (xs >= -1.0f && xs <= (float)W) ? 1.0f : 0.0f;
        const float x  = fminf(fmaxf(xs, 0.0f), (float)(W - 1));
        const float xf = floorf(x);
        s_lx[k] = x - xf;
        const int x0 = (int)xf;
        s_x0[k] = x0 * (C_CH / 2);
        s_x1[k] = min(x0 + 1, W - 1) * (C_CH / 2);
    }
    __syncthreads();

    if (t < 196) {
        const int sy = t / 14, sx = t - 14 * sy;
        const float ly = s_ly[sy], lx = s_lx[sx];
        const float v  = 0.25f * s_vy[sy] * s_vx[sx];
        const float hy = v * ly;
        const float my = v - hy;
        s_w[sy][sx] = make_float4(my - my * lx, my * lx, hy - hy * lx, hy * lx);
    }
    __syncthreads();

    const int g  = t >> 7;                 // row group: 0 -> bins 0..3, 1 -> 3..6
    const int c2 = t & 127;                // channel pair (channels 2c2, 2c2+1)
    const __half2* __restrict__ cbase =
        (const __half2*)ft + (size_t)b * P * (C_CH / 2) + c2;

    const int i0 = g ? 3 : 0;
    float prevx[7], prevy[7];
    float2* __restrict__ sOut = s_out2 + c2 * 36;   // 36 float2 per pair

    for (int i = i0; i < i0 + 4; ++i) {
        float curx[7], cury[7];
        #pragma unroll
        for (int j = 0; j < 7; ++j) { curx[j] = 0.0f; cury[j] = 0.0f; }

        #pragma unroll
        for (int syk = 0; syk < 2; ++syk) {
            const int sy = 2 * i + syk;
            const __half2* __restrict__ q0 = cbase + s_y0[sy];
            const __half2* __restrict__ q1 = cbase + s_y1[sy];
            #pragma unroll
            for (int j = 0; j < 7; ++j) {
                #pragma unroll
                for (int sxk = 0; sxk < 2; ++sxk) {
                    const int sx = 2 * j + sxk;
                    const float4 w = s_w[sy][sx];
                    const int xa = s_x0[sx], xb = s_x1[sx];
                    const __half2 h00 = q0[xa], h01 = q0[xb];
                    const __half2 h10 = q1[xa], h11 = q1[xb];
                    curx[j] += w.x * __low2float(h00)  + w.y * __low2float(h01)
                             + w.z * __low2float(h10)  + w.w * __low2float(h11);
                    cury[j] += w.x * __high2float(h00) + w.y * __high2float(h01)
                             + w.z * __high2float(h10) + w.w * __high2float(h11);
                }
            }
        }

        if (i > i0) {
            const int row = i - 1;         // global pooled row 0..5
            #pragma unroll
            for (int j = 0; j < 6; ++j) {
                sOut[row * 6 + j] = make_float2(
                    0.25f * (prevx[j] + prevx[j + 1] + curx[j] + curx[j + 1]),
                    0.25f * (prevy[j] + prevy[j + 1] + cury[j] + cury[j + 1]));
            }
        }
        #pragma unroll
        for (int j = 0; j < 7; ++j) { prevx[j] = curx[j]; prevy[j] = cury[j]; }
    }

    __syncthreads();
    // coalesced store of the ROI's 9216 outputs (ch-major: ch*36 + k)
    const float* __restrict__ sflat = (const float*)s_out2;
    float* __restrict__ orow = out + (size_t)roi * (C_CH * 36);
    #pragma unroll
    for (int e = t; e < C_CH * 36; e += 256) {
        const int cc = e / 36;
        const int kk = e - 36 * cc;
        orow[e] = sflat[(cc >> 1) * 72 + 2 * kk + (cc & 1)];
    }
}

// ---------------- fallback: direct fp32 gather (no workspace) ----------------
__global__ __launch_bounds__(256) void roialign_direct_kernel(
    const float* __restrict__ f0, const float* __restrict__ f1,
    const float* __restrict__ f2, const float* __restrict__ f3,
    const float* __restrict__ rois, float* __restrict__ out)
{
    const int roi = blockIdx.x;
    const int b   = roi / N_ROI;
    const float* r = rois + (size_t)roi * 7;

    __shared__ int   s_y0[14], s_y1[14], s_x0[14], s_x1[14];
    __shared__ float s_ly[14], s_lx[14], s_vy[14], s_vx[14];

    const int lev = (int)r[6];
    int H; const float* f;
    if      (lev == 0) { H = 160; f = f0; }
    else if (lev == 1) { H = 80;  f = f1; }
    else if (lev == 2) { H = 40;  f = f2; }
    else               { H = 20;  f = f3; }
    const int W = H;
    const float scale = (8.0f * (float)H) / (float)H0;
    const float x1 = r[1] * scale, y1 = r[2] * scale;
    const float x2 = r[3] * scale, y2 = r[4] * scale;
    const float bw = fmaxf(x2 - x1, 1.0f) * (1.0f / (float)PH);
    const float bh = fmaxf(y2 - y1, 1.0f) * (1.0f / (float)PH);

    const int t = threadIdx.x;
    if (t < 14) {
        const float off = (float)(t >> 1) + 0.25f + 0.5f * (float)(t & 1);
        const float ys  = y1 + off * bh;
        s_vy[t] = (ys >= -1.0f && ys <= (float)H) ? 1.0f : 0.0f;
        const float y  = fminf(fmaxf(ys, 0.0f), (float)(H - 1));
        const float yf = floorf(y);
        s_ly[t] = y - yf;
        const int y0 = (int)yf;
        s_y0[t] = y0 * W;
        s_y1[t] = min(y0 + 1, H - 1) * W;
    } else if (t < 28) {
        const int k = t - 14;
        const float off = (float)(k >> 1) + 0.25f + 0.5f * (float)(k & 1);
        const float xs  = x1 + off * bw;
        s_vx[k] = (xs >= -1.0f && xs <= (float)W) ? 1.0f : 0.0f;
        const float x  = fminf(fmaxf(xs, 0.0f), (float)(W - 1));
        const float xf = floorf(x);
        s_lx[k] = x - xf;
        const int x0 = (int)xf;
        s_x0[k] = x0;
        s_x1[k] = min(x0 + 1, W - 1);
    }
    __syncthreads();

    const int c = t;
    const float* __restrict__ fc = f + ((size_t)b * C_CH + c) * (size_t)(H * W);
    float* __restrict__ o_base = out + (size_t)roi * (C_CH * 36) + (size_t)c * 36;
    float prev[PH];

    for (int i = 0; i < PH; ++i) {
        const int   sy0 = 2 * i, sy1 = 2 * i + 1;
        const float lya = s_ly[sy0], vya = s_vy[sy0];
        const float lyb = s_ly[sy1], vyb = s_vy[sy1];
        const float* ra0 = fc + s_y0[sy0];
        const float* ra1 = fc + s_y1[sy0];
        const float* rb0 = fc + s_y0[sy1];
        const float* rb1 = fc + s_y1[sy1];
        float cur[PH];
        #pragma unroll
        for (int j = 0; j < PH; ++j) {
            float acc = 0.0f;
            #pragma unroll
            for (int sj = 0; sj < 2; ++sj) {
                const int   sx = 2 * j + sj;
                const int   x0 = s_x0[sx], x1i = s_x1[sx];
                const float lx = s_lx[sx], vx = s_vx[sx];
                {
                    const float f00 = ra0[x0], f01 = ra0[x1i];
                    const float f10 = ra1[x0], f11 = ra1[x1i];
                    const float top = f00 + lx * (f01 - f00);
                    const float bot = f10 + lx * (f11 - f10);
                    acc += (vya * vx) * (top + lya * (bot - top));
                }
                {
                    const float f00 = rb0[x0], f01 = rb0[x1i];
                    const float f10 = rb1[x0], f11 = rb1[x1i];
                    const float top = f00 + lx * (f01 - f00);
                    const float bot = f10 + lx * (f11 - f10);
                    acc += (vyb * vx) * (top + lyb * (bot - top));
                }
            }
            cur[j] = acc * 0.25f;
        }
        if (i > 0) {
            float* o = o_base + (size_t)(i - 1) * 6;
            #pragma unroll
            for (int j = 0; j < 6; ++j)
                o[j] = 0.25f * (prev[j] + prev[j + 1] + cur[j] + cur[j + 1]);
        }
        #pragma unroll
        for (int j = 0; j < PH; ++j) prev[j] = cur[j];
    }
}

extern "C" void kernel_launch(void* const* d_in, const int* in_sizes, int n_in,
                              void* d_out, int out_size, void* d_ws, size_t ws_size,
                              hipStream_t stream) {
    const float* f0   = (const float*)d_in[0];
    const float* f1   = (const float*)d_in[1];
    const float* f2   = (const float*)d_in[2];
    const float* f3   = (const float*)d_in[3];
    const float* rois = (const float*)d_in[4];
    float* out = (float*)d_out;

    const int n_rois = in_sizes[4] / 7;   // B*N = 1024
    const size_t need = WS_HALFS * sizeof(__half);

    if (d_ws != nullptr && ws_size >= need) {
        __half* ws = (__half*)d_ws;
        transpose_f16_kernel<<<NB_ALL, 256, 0, stream>>>(f0, f1, f2, f3, ws);
        roialign_kernel<<<n_rois, 256, 0, stream>>>(ws, rois, out);
    } else {
        roialign_direct_kernel<<<n_rois, 256, 0, stream>>>(f0, f1, f2, f3, rois, out);
    }
}